// Round 1
// baseline (242.619 us; speedup 1.0000x reference)
//
#include <hip/hip_runtime.h>

// FDN reverb == 8-tap sparse FIR + 50/50 mix + global max-abs normalize.
// Delays are compile-time constants: int(d_sec * 48000).
#define T_LEN 8388608
#define NTAPS 8

__device__ __constant__ int kDelays[NTAPS] = {1425, 1780, 1972, 2097, 2558, 2961, 3508, 3825};

// Compute combined[n] = g[n] * sum_j Q[j*8+n] into shared mem (tiny, per block).
__device__ inline void load_combined(const float* __restrict__ g,
                                     const float* __restrict__ Q,
                                     float* c /* shared, 8 */) {
    int tid = threadIdx.x;
    if (tid < NTAPS) {
        float s = 0.f;
#pragma unroll
        for (int j = 0; j < NTAPS; ++j) s += Q[j * NTAPS + tid];
        c[tid] = s * g[tid];
    }
    __syncthreads();
}

__device__ inline float compute_out(const float* __restrict__ x, int t,
                                    float xv, const float* c) {
    float wet = 0.f;
#pragma unroll
    for (int n = 0; n < NTAPS; ++n) {
        int s = t - kDelays[n];
        float tap = (s >= 0) ? x[s] : 0.f;
        wet = fmaf(c[n], tap, wet);
    }
    return 0.5f * wet + 0.5f * xv;
}

__global__ __launch_bounds__(256) void fdn_max_kernel(
    const float* __restrict__ x, const float* __restrict__ g,
    const float* __restrict__ Q, unsigned int* __restrict__ maxbits) {
    __shared__ float c[NTAPS];
    __shared__ float wmax[4];
    load_combined(g, Q, c);

    int tid = threadIdx.x;
    int t0 = (blockIdx.x * 256 + tid) * 4;
    float4 xv = *(const float4*)(x + t0);

    float m = 0.f;
    {
        float v;
        v = compute_out(x, t0 + 0, xv.x, c); m = fmaxf(m, fabsf(v));
        v = compute_out(x, t0 + 1, xv.y, c); m = fmaxf(m, fabsf(v));
        v = compute_out(x, t0 + 2, xv.z, c); m = fmaxf(m, fabsf(v));
        v = compute_out(x, t0 + 3, xv.w, c); m = fmaxf(m, fabsf(v));
    }

    // wave-64 reduce
#pragma unroll
    for (int off = 32; off > 0; off >>= 1) m = fmaxf(m, __shfl_down(m, off, 64));
    if ((tid & 63) == 0) wmax[tid >> 6] = m;
    __syncthreads();
    if (tid == 0) {
        float bm = fmaxf(fmaxf(wmax[0], wmax[1]), fmaxf(wmax[2], wmax[3]));
        // m >= 0 so float bits compare correctly as unsigned.
        atomicMax(maxbits, __float_as_uint(bm));
    }
}

__global__ __launch_bounds__(256) void fdn_out_kernel(
    const float* __restrict__ x, const float* __restrict__ g,
    const float* __restrict__ Q, const unsigned int* __restrict__ maxbits,
    float* __restrict__ out) {
    __shared__ float c[NTAPS];
    load_combined(g, Q, c);

    float inv = 1.0f / __uint_as_float(*maxbits);

    int tid = threadIdx.x;
    int t0 = (blockIdx.x * 256 + tid) * 4;
    float4 xv = *(const float4*)(x + t0);

    float4 ov;
    ov.x = compute_out(x, t0 + 0, xv.x, c) * inv;
    ov.y = compute_out(x, t0 + 1, xv.y, c) * inv;
    ov.z = compute_out(x, t0 + 2, xv.z, c) * inv;
    ov.w = compute_out(x, t0 + 3, xv.w, c) * inv;
    *(float4*)(out + t0) = ov;
}

extern "C" void kernel_launch(void* const* d_in, const int* in_sizes, int n_in,
                              void* d_out, int out_size, void* d_ws, size_t ws_size,
                              hipStream_t stream) {
    const float* x = (const float*)d_in[0];       // input_sig [1, T]
    const float* g = (const float*)d_in[1];       // feedback_gain [8]
    const float* Q = (const float*)d_in[2];       // orthogonal_matrix [8,8]
    float* out = (float*)d_out;
    unsigned int* maxbits = (unsigned int*)d_ws;

    // ws is re-poisoned to 0xAA before every timed launch — zero the max slot.
    hipMemsetAsync(d_ws, 0, sizeof(unsigned int), stream);

    // T_LEN = 2^23, each thread handles 4 elements -> exact division.
    dim3 block(256);
    dim3 grid(T_LEN / (256 * 4));
    fdn_max_kernel<<<grid, block, 0, stream>>>(x, g, Q, maxbits);
    fdn_out_kernel<<<grid, block, 0, stream>>>(x, g, Q, maxbits, out);
}

// Round 2
// 119.568 us; speedup vs baseline: 2.0291x; 2.0291x over previous
//
#include <hip/hip_runtime.h>

// FDN reverb == 8-tap sparse FIR + 50/50 mix + global max-abs normalize.
// Delays: int(d_sec * 48000) = {1425,1780,1972,2097,2558,2961,3508,3825}.
#define T_LEN 8388608
#define NTAPS 8
#define CHUNK 4096               // outputs per block
#define HALO  3840               // >= max delay (3825), multiple of 4
#define LDSF  (HALO + CHUNK)     // 7936 floats = 31 KB -> 5 blocks/CU

#define D0 1425
#define D1 1780
#define D2 1972
#define D3 2097
#define D4 2558
#define D5 2961
#define D6 3508
#define D7 3825

// Pass 1: stage chunk+halo in LDS, compute unnormalized out, write it,
// and reduce global max|out| via one atomicMax per block.
__global__ __launch_bounds__(256) void fdn_pass1(
    const float* __restrict__ x, const float* __restrict__ g,
    const float* __restrict__ Q, float* __restrict__ out,
    unsigned int* __restrict__ maxbits) {
    __shared__ __align__(16) float smem[LDSF];
    __shared__ float csh[NTAPS];
    __shared__ float wmax[4];

    const int tid = threadIdx.x;

    // combined[n] = g[n] * sum_j Q[j,n]  (tiny)
    if (tid < NTAPS) {
        float s = 0.f;
#pragma unroll
        for (int j = 0; j < NTAPS; ++j) s += Q[j * NTAPS + tid];
        csh[tid] = s * g[tid];
    }

    // Stage [blk*CHUNK - HALO, blk*CHUNK + CHUNK) into LDS; zeros before t=0.
    const long gs = (long)blockIdx.x * CHUNK - HALO;   // float index, 16B aligned
    for (int v = tid; v < LDSF / 4; v += 256) {
        long ga = gs + (long)v * 4;
        float4 val;
        if (ga >= 0) val = *(const float4*)(x + ga);
        else         val = make_float4(0.f, 0.f, 0.f, 0.f);
        *(float4*)(smem + v * 4) = val;
    }
    __syncthreads();

    float c0 = csh[0], c1 = csh[1], c2 = csh[2], c3 = csh[3];
    float c4 = csh[4], c5 = csh[5], c6 = csh[6], c7 = csh[7];

    const int base = blockIdx.x * CHUNK;
    float m = 0.f;
#pragma unroll
    for (int i = 0; i < CHUNK / 256; ++i) {
        const int j = i * 256 + tid;            // lane-consecutive -> no bank conflicts
        const float* p = smem + HALO + j;
        float wet = 0.f;
        wet = fmaf(c0, p[-D0], wet);
        wet = fmaf(c1, p[-D1], wet);
        wet = fmaf(c2, p[-D2], wet);
        wet = fmaf(c3, p[-D3], wet);
        wet = fmaf(c4, p[-D4], wet);
        wet = fmaf(c5, p[-D5], wet);
        wet = fmaf(c6, p[-D6], wet);
        wet = fmaf(c7, p[-D7], wet);
        float v = fmaf(0.5f, wet, 0.5f * p[0]);
        out[base + j] = v;                      // coalesced scalar stores
        m = fmaxf(m, fabsf(v));
    }

    // wave-64 reduce, then block reduce, one atomic per block
#pragma unroll
    for (int off = 32; off > 0; off >>= 1) m = fmaxf(m, __shfl_down(m, off, 64));
    if ((tid & 63) == 0) wmax[tid >> 6] = m;
    __syncthreads();
    if (tid == 0) {
        float bm = fmaxf(fmaxf(wmax[0], wmax[1]), fmaxf(wmax[2], wmax[3]));
        atomicMax(maxbits, __float_as_uint(bm));  // values >= 0: bit compare OK
    }
}

// Pass 2: pure streaming rescale at HBM ceiling.
__global__ __launch_bounds__(256) void fdn_scale(
    float* __restrict__ out, const unsigned int* __restrict__ maxbits) {
    const float inv = 1.0f / __uint_as_float(*maxbits);
    const int i = (blockIdx.x * 256 + threadIdx.x) * 4;
    float4 v = *(const float4*)(out + i);
    v.x *= inv; v.y *= inv; v.z *= inv; v.w *= inv;
    *(float4*)(out + i) = v;
}

extern "C" void kernel_launch(void* const* d_in, const int* in_sizes, int n_in,
                              void* d_out, int out_size, void* d_ws, size_t ws_size,
                              hipStream_t stream) {
    const float* x = (const float*)d_in[0];       // input_sig [1, T]
    const float* g = (const float*)d_in[1];       // feedback_gain [8]
    const float* Q = (const float*)d_in[2];       // orthogonal_matrix [8,8]
    float* out = (float*)d_out;
    unsigned int* maxbits = (unsigned int*)d_ws;

    hipMemsetAsync(d_ws, 0, sizeof(unsigned int), stream);

    fdn_pass1<<<dim3(T_LEN / CHUNK), dim3(256), 0, stream>>>(x, g, Q, out, maxbits);
    fdn_scale<<<dim3(T_LEN / (256 * 4)), dim3(256), 0, stream>>>(out, maxbits);
}